// Round 8
// baseline (215.967 us; speedup 1.0000x reference)
//
#include <hip/hip_runtime.h>
#include <hip/hip_bf16.h>
#include <cstdint>

// MultiHeadSelfAttention: B=4 S=4096 E=768 H=8 D=96. Inputs/outputs f32.
// Pipeline: weight f32->bf16 prepass -> QKV GEMMs (A: f32 reg-staged with
// fused cvt_pk conversion under counted-vmcnt schedule; W: bf16
// global_load_lds; 256x192 tile, 8 waves, BK=64 dbuf LDS, 4 phases/K-tile,
// raw s_barrier, drain only at iter boundary, setprio around MFMA) ->
// per-token 8x8 head-gram attention -> scrambled reshape -> output GEMM
// + bias (f32 out, A bf16 via global_load_lds).

typedef unsigned short u16;
typedef short bf16x8 __attribute__((ext_vector_type(8)));
typedef float f32x4 __attribute__((ext_vector_type(4)));

#define B_  4
#define S_  4096
#define E_  768
#define H_  8
#define D_  96
#define T_  (B_*S_)            // 16384 tokens
#define BM_ 256
#define BN_ 192

static __device__ __forceinline__ u16 f2bf(float f) {
  unsigned u = __builtin_bit_cast(unsigned, f);
  u += 0x7fffu + ((u >> 16) & 1u);           // round-to-nearest-even
  return (u16)(u >> 16);
}
static __device__ __forceinline__ unsigned pk2(float lo, float hi) {
  return (unsigned)f2bf(lo) | ((unsigned)f2bf(hi) << 16);
}
// HW packed convert (RNE): dst = {bf16(lo), bf16(hi)}
static __device__ __forceinline__ unsigned cvtpk(float lo, float hi) {
  unsigned r;
  asm("v_cvt_pk_bf16_f32 %0, %1, %2" : "=v"(r) : "v"(lo), "v"(hi));
  return r;
}
static __device__ __forceinline__ float bflo(unsigned u) {
  return __builtin_bit_cast(float, u << 16);
}
static __device__ __forceinline__ float bfhi(unsigned u) {
  return __builtin_bit_cast(float, u & 0xffff0000u);
}

// ---------------- f32 -> bf16 convert, all 4 weight matrices (E*E each)
__global__ __launch_bounds__(256) void conv_w(
    const float* __restrict__ w0, const float* __restrict__ w1,
    const float* __restrict__ w2, const float* __restrict__ w3,
    u16* __restrict__ dst)
{
  const int bpw = (E_ * E_ / 4) / 256;            // 576 blocks per weight
  const int which = blockIdx.x / bpw;
  const float* src = which == 0 ? w0 : which == 1 ? w1 : which == 2 ? w2 : w3;
  const int i = (blockIdx.x - which * bpw) * 256 + threadIdx.x;
  const float4 v = ((const float4*)src)[i];
  uint2 w;
  w.x = pk2(v.x, v.y);
  w.y = pk2(v.z, v.w);
  ((uint2*)(dst + (size_t)which * E_ * E_))[i] = w;
}

// ---------------- GEMM: C[T_,E_] = A[T_,E_] x W[E_,E_](bf16)^T (+bias)
// 256x192 tile, BK=64, 512 thr (8 waves, 2M x 4N; wave tile 128x48).
// LDS: A 256x64 (32KB) + B 192x64 (24KB), double-buffered = 112KB.
// Swizzle: 16B-granule g of row r stored at slot g ^ (r&7).
// A_F32: A staged global->reg (f32) in phase 0, cvt_pk+ds_write in phase 3
// (T14 issue-early/write-late); else A bf16 via global_load_lds.

#define GLOAD(SRC, DST)                                                        \
  __builtin_amdgcn_global_load_lds(                                            \
      (const __attribute__((address_space(1))) void*)(SRC),                    \
      (__attribute__((address_space(3))) void*)(DST), 16, 0, 0)

#define SA(BUF, I, KT) GLOAD(sA[I] + (KT), &lA[BUF][(((I) << 3) + wave) * 512])
#define SB(BUF, I, KT) GLOAD(sB[I] + (KT), &lB[BUF][(((I) << 3) + wave) * 512])

// f32-A staging: thread covers row ar, f32 cols ah*32..+31 (8 float4)
#define A_ISSUE(KT)                                                            \
  {                                                                            \
    _Pragma("unroll")                                                          \
    for (int w_ = 0; w_ < 8; ++w_)                                             \
      av[w_] = *(const float4*)(agp + (KT) + (w_ << 2));                       \
  }
// pack 32 f32 -> 4 granules, write at swizzled slots of lA[BUF]
#define A_WRITE(BUF)                                                           \
  {                                                                            \
    _Pragma("unroll")                                                          \
    for (int w_ = 0; w_ < 4; ++w_) {                                           \
      uint4 q_;                                                                \
      q_.x = cvtpk(av[2 * w_].x, av[2 * w_].y);                                \
      q_.y = cvtpk(av[2 * w_].z, av[2 * w_].w);                                \
      q_.z = cvtpk(av[2 * w_ + 1].x, av[2 * w_ + 1].y);                        \
      q_.w = cvtpk(av[2 * w_ + 1].z, av[2 * w_ + 1].w);                        \
      *(uint4*)&lA[BUF][ar * 64 + ((((ah << 2) + w_) ^ (ar & 7)) << 3)] = q_;  \
    }                                                                          \
  }

#define MFMA12(MB)                                                             \
  {                                                                            \
    _Pragma("unroll")                                                          \
    for (int m_ = 0; m_ < 4; ++m_) {                                           \
      acc[(MB) + m_][0] = __builtin_amdgcn_mfma_f32_16x16x32_bf16(a[m_], b[0], acc[(MB) + m_][0], 0, 0, 0); \
      acc[(MB) + m_][1] = __builtin_amdgcn_mfma_f32_16x16x32_bf16(a[m_], b[1], acc[(MB) + m_][1], 0, 0, 0); \
      acc[(MB) + m_][2] = __builtin_amdgcn_mfma_f32_16x16x32_bf16(a[m_], b[2], acc[(MB) + m_][2], 0, 0, 0); \
    }                                                                          \
  }

template<bool A_F32, bool OUT_F32, bool BIAS>
__global__ __launch_bounds__(512, 2) void gemm_big(
    const void* __restrict__ Av, const u16* __restrict__ Wt,
    const float* __restrict__ bias, void* __restrict__ Cv)
{
  __shared__ u16 lA[2][256 * 64];                 // 64 KB
  __shared__ u16 lB[2][192 * 64];                 // 48 KB
  const int tid = threadIdx.x, wave = tid >> 6, lane = tid & 63;
  const int wr = wave >> 2, wcn = wave & 3;       // 2M x 4N wave grid
  // XCD-chunked swizzle (256 blocks, 32/XCD = 8 M-panels x 4 N)
  const int wg = ((blockIdx.x & 7) << 5) + (blockIdx.x >> 3);
  const int tM = (wg >> 2) << 8, tN = (wg & 3) * BN_;
  const int l15 = lane & 15, l4 = lane >> 4;
  // gload_lds staging geometry: chunk = i*8+wave covers 8 rows (1KB)
  const int srow = lane >> 3;
  const int sg   = (lane & 7) ^ srow;             // source granule pre-swizzle

  const u16* A16 = (const u16*)Av;
  const float* A32 = (const float*)Av;

  const u16* sA[4];
  const u16* sB[3];
#pragma unroll
  for (int i = 0; i < 3; ++i)
    sB[i] = Wt + (size_t)(tN + (((i << 3) + wave) << 3) + srow) * E_ + (sg << 3);
  if constexpr (!A_F32) {
#pragma unroll
    for (int i = 0; i < 4; ++i)
      sA[i] = A16 + (size_t)(tM + (((i << 3) + wave) << 3) + srow) * E_ + (sg << 3);
  }
  // f32-A staging geometry
  const int ar = tid >> 1, ah = tid & 1;
  const float* agp = A32 + (size_t)(tM + ar) * E_ + (ah << 5);

  f32x4 acc[8][3] = {};
  float4 av[8];

  // prologue: stage K-tile 0 into buf 0, drain everything, barrier
  if constexpr (A_F32) {
    A_ISSUE(0);
#pragma unroll
    for (int i = 0; i < 3; ++i) SB(0, i, 0);
    A_WRITE(0);
  } else {
#pragma unroll
    for (int i = 0; i < 4; ++i) SA(0, i, 0);
#pragma unroll
    for (int i = 0; i < 3; ++i) SB(0, i, 0);
  }
  __syncthreads();

  for (int t = 0; t < 12; ++t) {
    const int cur = t & 1, nxt = cur ^ 1;
    const int ktn = (t + 1) << 6;
    const bool pf = (t < 11);
    bf16x8 a[4], b[3];

    // -------- phase 0: kk=0, mh=0; issue A prefetch (f32 regs or gload_lds)
#pragma unroll
    for (int m = 0; m < 4; ++m) {
      const int row = (wr << 7) + (m << 4) + l15;
      a[m] = *(const bf16x8*)&lA[cur][row * 64 + ((l4 ^ (row & 7)) << 3)];
    }
#pragma unroll
    for (int n = 0; n < 3; ++n) {
      const int row = wcn * 48 + (n << 4) + l15;
      b[n] = *(const bf16x8*)&lB[cur][row * 64 + ((l4 ^ (row & 7)) << 3)];
    }
    if (pf) {
      if constexpr (A_F32) { A_ISSUE(ktn); }
      else { SA(nxt, 0, ktn); SA(nxt, 1, ktn); SA(nxt, 2, ktn); }
    }
    __builtin_amdgcn_s_barrier();
    __builtin_amdgcn_s_setprio(1);
    MFMA12(0);
    __builtin_amdgcn_s_setprio(0);
    __builtin_amdgcn_s_barrier();

    // -------- phase 1: kk=0, mh=1; reuse b; stage B (and A3 if bf16 path)
#pragma unroll
    for (int m = 0; m < 4; ++m) {
      const int row = (wr << 7) + 64 + (m << 4) + l15;
      a[m] = *(const bf16x8*)&lA[cur][row * 64 + ((l4 ^ (row & 7)) << 3)];
    }
    if (pf) {
      if constexpr (A_F32) { SB(nxt, 0, ktn); SB(nxt, 1, ktn); SB(nxt, 2, ktn); }
      else { SA(nxt, 3, ktn); SB(nxt, 0, ktn); }
    }
    __builtin_amdgcn_s_barrier();
    __builtin_amdgcn_s_setprio(1);
    MFMA12(4);
    __builtin_amdgcn_s_setprio(0);
    __builtin_amdgcn_s_barrier();

    // -------- phase 2: kk=1, mh=0
#pragma unroll
    for (int m = 0; m < 4; ++m) {
      const int row = (wr << 7) + (m << 4) + l15;
      a[m] = *(const bf16x8*)&lA[cur][row * 64 + (((4 + l4) ^ (row & 7)) << 3)];
    }
#pragma unroll
    for (int n = 0; n < 3; ++n) {
      const int row = wcn * 48 + (n << 4) + l15;
      b[n] = *(const bf16x8*)&lB[cur][row * 64 + (((4 + l4) ^ (row & 7)) << 3)];
    }
    if (pf) {
      if constexpr (!A_F32) { SB(nxt, 1, ktn); SB(nxt, 2, ktn); }
    }
    __builtin_amdgcn_s_barrier();
    __builtin_amdgcn_s_setprio(1);
    MFMA12(0);
    __builtin_amdgcn_s_setprio(0);
    __builtin_amdgcn_s_barrier();

    // -------- phase 3: kk=1, mh=1; then A cvt+write (f32 path), drains
#pragma unroll
    for (int m = 0; m < 4; ++m) {
      const int row = (wr << 7) + 64 + (m << 4) + l15;
      a[m] = *(const bf16x8*)&lA[cur][row * 64 + (((4 + l4) ^ (row & 7)) << 3)];
    }
    __builtin_amdgcn_s_barrier();
    __builtin_amdgcn_s_setprio(1);
    MFMA12(4);
    __builtin_amdgcn_s_setprio(0);
    if (pf) {
      if constexpr (A_F32) {
        A_WRITE(nxt);                               // vmcnt for av auto-inserted
        asm volatile("s_waitcnt lgkmcnt(0)" ::: "memory");  // ds_writes visible
      }
      // boundary: own prefetch gloads must be done before next tile reads
      asm volatile("s_waitcnt vmcnt(0)" ::: "memory");
    }
    __builtin_amdgcn_s_barrier();
  }

  // epilogue: C/D layout col=lane&15, row=(lane>>4)*4+reg  [m89/m91]
  const int cr = l4 << 2;
#pragma unroll
  for (int m = 0; m < 8; ++m) {
#pragma unroll
    for (int n = 0; n < 3; ++n) {
      const int row = tM + (wr << 7) + (m << 4) + cr;
      const int col = tN + wcn * 48 + (n << 4) + l15;
      const float badd = BIAS ? bias[col] : 0.f;
#pragma unroll
      for (int r = 0; r < 4; ++r) {
        const float val = acc[m][n][r] + badd;
        if constexpr (OUT_F32)
          ((float*)Cv)[(size_t)(row + r) * E_ + col] = val;
        else
          ((u16*)Cv)[(size_t)(row + r) * E_ + col] = f2bf(val);
      }
    }
  }
}

// ---------------- per-token attention: 1 wave per token
// att[i,j] = sum_d Q[t,i*96+d]*K[t,j*96+d]; masked softmax over j;
// out2D[b, 512*i + s/8, 96*(s%8)+d] = sum_j p[i,j]*V[t, j*96+d]
__global__ __launch_bounds__(256) void attn_tok(
    const u16* __restrict__ Q, const u16* __restrict__ K,
    const u16* __restrict__ V, const int* __restrict__ mask,
    u16* __restrict__ O)
{
  __shared__ float pl[4][8][8];
  const int tid = threadIdx.x, wave = tid >> 6, lane = tid & 63;
  const int t = blockIdx.x * 4 + wave;
  const int s = t & (S_ - 1);
  const int b = t >> 12;
  const int i = lane >> 3, j = lane & 7;

  const uint4* qp = (const uint4*)(Q + (size_t)t * E_ + i * D_);
  const uint4* kp = (const uint4*)(K + (size_t)t * E_ + j * D_);
  float acc = 0.f;
#pragma unroll
  for (int it = 0; it < 12; ++it) {   // 96 bf16 = 12 x uint4
    const uint4 qv = qp[it], kv = kp[it];
    acc += bflo(qv.x) * bflo(kv.x) + bfhi(qv.x) * bfhi(kv.x);
    acc += bflo(qv.y) * bflo(kv.y) + bfhi(qv.y) * bfhi(kv.y);
    acc += bflo(qv.z) * bflo(kv.z) + bfhi(qv.z) * bfhi(kv.z);
    acc += bflo(qv.w) * bflo(kv.w) + bfhi(qv.w) * bfhi(kv.w);
  }
  // mask==0 -> -1e20 everywhere -> softmax degenerates to 1/8
  float sv = (mask[t] == 0) ? -1e20f : acc;
  sv *= 0.03608439182435161f;          // 1/sqrt(768)
  float mx = sv;
  mx = fmaxf(mx, __shfl_xor(mx, 1));
  mx = fmaxf(mx, __shfl_xor(mx, 2));
  mx = fmaxf(mx, __shfl_xor(mx, 4));
  const float e = __expf(sv - mx);
  float sm = e;
  sm += __shfl_xor(sm, 1);
  sm += __shfl_xor(sm, 2);
  sm += __shfl_xor(sm, 4);
  pl[wave][i][j] = e / sm;
  __syncthreads();

  // PV: lane (i2, db) owns d = db*12 .. db*12+11 of head i2
  const int i2 = lane >> 3, db = lane & 7;
  float o[12] = {};
#pragma unroll
  for (int jj = 0; jj < 8; ++jj) {
    const float pj = pl[wave][i2][jj];
    const uint2* vp = (const uint2*)(V + (size_t)t * E_ + jj * D_ + db * 12);
    const uint2 v0 = vp[0], v1 = vp[1], v2 = vp[2];
    o[0]  += pj * bflo(v0.x);  o[1]  += pj * bfhi(v0.x);
    o[2]  += pj * bflo(v0.y);  o[3]  += pj * bfhi(v0.y);
    o[4]  += pj * bflo(v1.x);  o[5]  += pj * bfhi(v1.x);
    o[6]  += pj * bflo(v1.y);  o[7]  += pj * bfhi(v1.y);
    o[8]  += pj * bflo(v2.x);  o[9]  += pj * bfhi(v2.x);
    o[10] += pj * bflo(v2.y);  o[11] += pj * bfhi(v2.y);
  }
  // scrambled reshape [b,h,s,d] -> [b, 512h + s/8, 96(s%8)+d]
  const size_t row = (size_t)b * S_ + 512 * i2 + (s >> 3);
  u16* op = O + row * E_ + 96 * (s & 7) + db * 12;
  uint2 w0, w1, w2;
  w0.x = pk2(o[0], o[1]);
  w0.y = pk2(o[2], o[3]);
  w1.x = pk2(o[4], o[5]);
  w1.y = pk2(o[6], o[7]);
  w2.x = pk2(o[8], o[9]);
  w2.y = pk2(o[10], o[11]);
  ((uint2*)op)[0] = w0;
  ((uint2*)op)[1] = w1;
  ((uint2*)op)[2] = w2;
}

extern "C" void kernel_launch(void* const* d_in, const int* in_sizes, int n_in,
                              void* d_out, int out_size, void* d_ws, size_t ws_size,
                              hipStream_t stream)
{
  const float* values = (const float*)d_in[0];
  const float* keys   = (const float*)d_in[1];
  const float* query  = (const float*)d_in[2];
  const int*   mask   = (const int*)d_in[3];
  const float* Wv = (const float*)d_in[4];
  const float* Wk = (const float*)d_in[5];
  const float* Wq = (const float*)d_in[6];
  const float* Wo = (const float*)d_in[7];
  const float* bo = (const float*)d_in[8];

  const size_t TE = (size_t)T_ * E_;
  const size_t EE = (size_t)E_ * E_;
  u16* Qb = (u16*)d_ws;          // 25.2 MB each (bf16)
  u16* Kb = Qb + TE;
  u16* Vb = Kb + TE;
  u16* O2 = Vb + TE;             // attention output (scrambled layout)
  u16* Wb = O2 + TE;             // 4 x 1.18 MB bf16 weights (105.4 MB total)

  dim3 gg(T_ / BM_ * (E_ / BN_));   // 64 x 4 = 256 blocks = 1/CU

  conv_w<<<dim3(4 * (E_ * E_ / 4) / 256), dim3(256), 0, stream>>>(Wq, Wk, Wv, Wo, Wb);

  gemm_big<true, false, false><<<gg, dim3(512), 0, stream>>>(query,  Wb + 0 * EE, nullptr, Qb);
  gemm_big<true, false, false><<<gg, dim3(512), 0, stream>>>(keys,   Wb + 1 * EE, nullptr, Kb);
  gemm_big<true, false, false><<<gg, dim3(512), 0, stream>>>(values, Wb + 2 * EE, nullptr, Vb);

  attn_tok<<<dim3(T_ / 4), dim3(256), 0, stream>>>(Qb, Kb, Vb, mask, O2);

  gemm_big<false, true, true><<<gg, dim3(512), 0, stream>>>(O2, Wb + 3 * EE, bo, (float*)d_out);
}

// Round 9
// 192.283 us; speedup vs baseline: 1.1232x; 1.1232x over previous
//
#include <hip/hip_runtime.h>
#include <hip/hip_bf16.h>
#include <cstdint>

// MultiHeadSelfAttention: B=4 S=4096 E=768 H=8 D=96. Inputs/outputs f32.
// Pipeline: f32->bf16 prepass (activations + weights) -> GEMMs (m201-style
// 256x256 8-phase template: BK=64, 8 waves, progressive half-tile
// consumption, counted vmcnt(4), setprio MFMA clusters) -> per-token 8x8
// head-gram attention -> scrambled reshape -> output GEMM + bias (f32 out).

typedef unsigned short u16;
typedef short bf16x8 __attribute__((ext_vector_type(8)));
typedef float f32x4 __attribute__((ext_vector_type(4)));

#define B_  4
#define S_  4096
#define E_  768
#define H_  8
#define D_  96
#define T_  (B_*S_)            // 16384 tokens

static __device__ __forceinline__ u16 f2bf(float f) {
  unsigned u = __builtin_bit_cast(unsigned, f);
  u += 0x7fffu + ((u >> 16) & 1u);           // round-to-nearest-even
  return (u16)(u >> 16);
}
static __device__ __forceinline__ unsigned pk2(float lo, float hi) {
  return (unsigned)f2bf(lo) | ((unsigned)f2bf(hi) << 16);
}
static __device__ __forceinline__ float bflo(unsigned u) {
  return __builtin_bit_cast(float, u << 16);
}
static __device__ __forceinline__ float bfhi(unsigned u) {
  return __builtin_bit_cast(float, u & 0xffff0000u);
}

// ---------------- f32 -> bf16 convert (activations), one tensor per launch
__global__ __launch_bounds__(256) void conv_bf16(
    const float* __restrict__ src, u16* __restrict__ dst)
{
  const int i = blockIdx.x * 256 + threadIdx.x;   // float4 index
  const float4 v = ((const float4*)src)[i];
  uint2 w;
  w.x = pk2(v.x, v.y);
  w.y = pk2(v.z, v.w);
  ((uint2*)dst)[i] = w;
}

// ---------------- f32 -> bf16 convert, all 4 weight matrices (E*E each)
__global__ __launch_bounds__(256) void conv_w(
    const float* __restrict__ w0, const float* __restrict__ w1,
    const float* __restrict__ w2, const float* __restrict__ w3,
    u16* __restrict__ dst)
{
  const int bpw = (E_ * E_ / 4) / 256;            // 576 blocks per weight
  const int which = blockIdx.x / bpw;
  const float* src = which == 0 ? w0 : which == 1 ? w1 : which == 2 ? w2 : w3;
  const int i = (blockIdx.x - which * bpw) * 256 + threadIdx.x;
  const float4 v = ((const float4*)src)[i];
  uint2 w;
  w.x = pk2(v.x, v.y);
  w.y = pk2(v.z, v.w);
  ((uint2*)(dst + (size_t)which * E_ * E_))[i] = w;
}

// ---------------- GEMM: C[T_,E_] = A[T_,E_](bf16) x W[E_,E_](bf16)^T (+bias)
// m201 8-phase template: 256x256 tile, BK=64, 512 thr (8 waves 2Mx4N).
// Wave output = quadrants (mh,nh): rows mh*128+wr*64+m*16, cols
// nh*128+wcn*32+n*16 -> each quadrant touches exactly ONE A-half / B-half,
// enabling progressive half-tile consumption + counted vmcnt(4).
// LDS: [2 buf][2 half][128x64] bf16 for A and B = 128 KB total.
// Swizzle: 16B-granule g of half-row r at slot g ^ (r&7).
// Stage schedule at tile t: p0:B1(t+1) p1:A1(t+1) p2:A0(t+2) p3:B0(t+2);
// one vmcnt(4) at end of p3 (0 at t=10). Invariant: at tile start, tile's
// 4 halves complete, 2 halves (A0/B0 of t+1) in flight.

#define GLOAD(SRC, DST)                                                        \
  __builtin_amdgcn_global_load_lds(                                            \
      (const __attribute__((address_space(1))) void*)(SRC),                    \
      (__attribute__((address_space(3))) void*)(DST), 16, 0, 0)

// half-tile stage: 2 gload_lds; dest row (c*8+wave)*8+(lane>>3), slot lane&7;
// source granule pre-swizzled: (lane&7)^(lane>>3)
#define STG_A(HALF, T)                                                         \
  {                                                                            \
    const int b_ = (T) & 1;                                                    \
    GLOAD(Abase + (size_t)(tM + (HALF)*128 + (wave<<3) + srow8) * E_ + ((T)<<6) + sgo, \
          &lds[(b_*2 + (HALF)) * 8192 + ((wave*64 + lane) << 3)]);             \
    GLOAD(Abase + (size_t)(tM + (HALF)*128 + 64 + (wave<<3) + srow8) * E_ + ((T)<<6) + sgo, \
          &lds[(b_*2 + (HALF)) * 8192 + (((8 + wave)*64 + lane) << 3)]);       \
  }
#define STG_B(HALF, T)                                                         \
  {                                                                            \
    const int b_ = (T) & 1;                                                    \
    GLOAD(Wbase + (size_t)(tN + (HALF)*128 + (wave<<3) + srow8) * E_ + ((T)<<6) + sgo, \
          &lds[32768 + (b_*2 + (HALF)) * 8192 + ((wave*64 + lane) << 3)]);     \
    GLOAD(Wbase + (size_t)(tN + (HALF)*128 + 64 + (wave<<3) + srow8) * E_ + ((T)<<6) + sgo, \
          &lds[32768 + (b_*2 + (HALF)) * 8192 + (((8 + wave)*64 + lane) << 3)]); \
  }

#define RD_A(DST, BUF, MH, KK)                                                 \
  {                                                                            \
    _Pragma("unroll")                                                          \
    for (int m_ = 0; m_ < 4; ++m_) {                                           \
      const int hr_ = (wr << 6) + (m_ << 4) + l15;                             \
      DST[m_] = *(const bf16x8*)&lds[((BUF)*2 + (MH)) * 8192 + hr_ * 64 +      \
                                     (((((KK) << 2) + l4) ^ (hr_ & 7)) << 3)]; \
    }                                                                          \
  }
#define RD_B(DST, BUF, NH, KK)                                                 \
  {                                                                            \
    _Pragma("unroll")                                                          \
    for (int n_ = 0; n_ < 2; ++n_) {                                           \
      const int hr_ = (wcn << 5) + (n_ << 4) + l15;                            \
      DST[n_] = *(const bf16x8*)&lds[32768 + ((BUF)*2 + (NH)) * 8192 + hr_ * 64 + \
                                     (((((KK) << 2) + l4) ^ (hr_ & 7)) << 3)]; \
    }                                                                          \
  }

#define MFMA16(MH, NH, B0N, B1N)                                               \
  {                                                                            \
    __builtin_amdgcn_s_setprio(1);                                             \
    _Pragma("unroll")                                                          \
    for (int m_ = 0; m_ < 4; ++m_) {                                           \
      _Pragma("unroll")                                                        \
      for (int n_ = 0; n_ < 2; ++n_) {                                         \
        acc[MH][NH][m_][n_] = __builtin_amdgcn_mfma_f32_16x16x32_bf16(a0[m_], B0N[n_], acc[MH][NH][m_][n_], 0, 0, 0); \
        acc[MH][NH][m_][n_] = __builtin_amdgcn_mfma_f32_16x16x32_bf16(a1[m_], B1N[n_], acc[MH][NH][m_][n_], 0, 0, 0); \
      }                                                                        \
    }                                                                          \
    __builtin_amdgcn_s_setprio(0);                                             \
  }

template<bool OUT_F32, bool BIAS>
__global__ __launch_bounds__(512, 2) void gemm8(
    const u16* __restrict__ Abase, const u16* __restrict__ Wbase,
    const float* __restrict__ bias, void* __restrict__ Cv)
{
  __shared__ u16 lds[65536];                      // 128 KB: A halves then B
  const int tid = threadIdx.x, wave = tid >> 6, lane = tid & 63;
  const int wr = wave >> 2, wcn = wave & 3;       // 2M x 4N wave grid
  // XCD swizzle: 192 blocks = 8 XCD x 24 (8 M-panels x 3 N)
  const int wg = (blockIdx.x & 7) * 24 + (blockIdx.x >> 3);
  const int tM = (wg / 3) << 8, tN = (wg % 3) << 8;
  const int l15 = lane & 15, l4 = lane >> 4;
  const int srow8 = lane >> 3;
  const int sgo = ((lane & 7) ^ srow8) << 3;      // pre-swizzled src granule

  f32x4 acc[2][2][4][2] = {};
  bf16x8 a0[4], a1[4], bh0k0[2], bh0k1[2], bh1k0[2], bh1k1[2];

  // prologue: 6 halves (tile0 all + tile1 A0,B0) = 12 loads; vmcnt(4)
  STG_A(0, 0); STG_B(0, 0); STG_B(1, 0); STG_A(1, 0);
  STG_A(0, 1); STG_B(0, 1);
  asm volatile("s_waitcnt vmcnt(4)" ::: "memory");
  __builtin_amdgcn_s_barrier();

  for (int t = 0; t < 12; ++t) {
    const int buf = t & 1;
    // ---- p0: Q(0,0) — reads A-half0 (kk0,1) + B-half0; stage B1(t+1)
    RD_A(a0, buf, 0, 0); RD_A(a1, buf, 0, 1);
    RD_B(bh0k0, buf, 0, 0); RD_B(bh0k1, buf, 0, 1);
    if (t < 11) STG_B(1, t + 1);
    __builtin_amdgcn_s_barrier();
    MFMA16(0, 0, bh0k0, bh0k1);
    __builtin_amdgcn_s_barrier();
    // ---- p1: Q(0,1) — reads B-half1 (reuse a); stage A1(t+1)
    RD_B(bh1k0, buf, 1, 0); RD_B(bh1k1, buf, 1, 1);
    if (t < 11) STG_A(1, t + 1);
    __builtin_amdgcn_s_barrier();
    MFMA16(0, 1, bh1k0, bh1k1);
    __builtin_amdgcn_s_barrier();
    // ---- p2: Q(1,0) — reads A-half1 + re-reads B-half0; stage A0(t+2)
    RD_A(a0, buf, 1, 0); RD_A(a1, buf, 1, 1);
    RD_B(bh0k0, buf, 0, 0); RD_B(bh0k1, buf, 0, 1);
    if (t < 10) STG_A(0, t + 2);
    __builtin_amdgcn_s_barrier();
    MFMA16(1, 0, bh0k0, bh0k1);
    __builtin_amdgcn_s_barrier();
    // ---- p3: Q(1,1) — no reads (reuse a + bh1); stage B0(t+2); tile wait
    if (t < 10) STG_B(0, t + 2);
    __builtin_amdgcn_s_barrier();
    MFMA16(1, 1, bh1k0, bh1k1);
    if (t < 10)       asm volatile("s_waitcnt vmcnt(4)" ::: "memory");
    else if (t == 10) asm volatile("s_waitcnt vmcnt(0)" ::: "memory");
    __builtin_amdgcn_s_barrier();
  }

  // epilogue: C/D layout col=lane&15, row=(lane>>4)*4+reg  [m89/m91]
  if constexpr (OUT_F32) {
#pragma unroll
    for (int mh = 0; mh < 2; ++mh)
#pragma unroll
      for (int nh = 0; nh < 2; ++nh)
#pragma unroll
        for (int m = 0; m < 4; ++m)
#pragma unroll
          for (int n = 0; n < 2; ++n) {
            const int row = tM + mh * 128 + (wr << 6) + (m << 4) + (l4 << 2);
            const int col = tN + nh * 128 + (wcn << 5) + (n << 4) + l15;
            const float badd = BIAS ? bias[col] : 0.f;
#pragma unroll
            for (int r = 0; r < 4; ++r)
              ((float*)Cv)[(size_t)(row + r) * E_ + col] = acc[mh][nh][m][n][r] + badd;
          }
  } else {
    // stage C tile (256x256 u16 = 128 KB) in LDS, write back coalesced.
    // granule swizzle g ^= ((row&3)<<1) to spread write/read banks.
    __builtin_amdgcn_s_barrier();
#pragma unroll
    for (int mh = 0; mh < 2; ++mh)
#pragma unroll
      for (int nh = 0; nh < 2; ++nh)
#pragma unroll
        for (int m = 0; m < 4; ++m)
#pragma unroll
          for (int n = 0; n < 2; ++n) {
            const int colb = nh * 128 + (wcn << 5) + (n << 4) + l15;
#pragma unroll
            for (int r = 0; r < 4; ++r) {
              const int row = mh * 128 + (wr << 6) + (m << 4) + (l4 << 2) + r;
              const int g = colb >> 3;
              lds[row * 256 + (((g ^ ((row & 3) << 1)) << 3) | (colb & 7))] =
                  f2bf(acc[mh][nh][m][n][r]);
            }
          }
    __builtin_amdgcn_s_barrier();
#pragma unroll
    for (int p = 0; p < 16; ++p) {
      const int row = (p << 4) + (tid >> 5);
      const int g = tid & 31;
      const bf16x8 v = *(const bf16x8*)&lds[row * 256 + ((g ^ ((row & 3) << 1)) << 3)];
      *(bf16x8*)((u16*)Cv + (size_t)(tM + row) * E_ + tN + (g << 3)) = v;
    }
  }
}

// ---------------- per-token attention: 1 wave per token
// att[i,j] = sum_d Q[t,i*96+d]*K[t,j*96+d]; masked softmax over j;
// out2D[b, 512*i + s/8, 96*(s%8)+d] = sum_j p[i,j]*V[t, j*96+d]
__global__ __launch_bounds__(256) void attn_tok(
    const u16* __restrict__ Q, const u16* __restrict__ K,
    const u16* __restrict__ V, const int* __restrict__ mask,
    u16* __restrict__ O)
{
  __shared__ float pl[4][8][8];
  const int tid = threadIdx.x, wave = tid >> 6, lane = tid & 63;
  const int t = blockIdx.x * 4 + wave;
  const int s = t & (S_ - 1);
  const int b = t >> 12;
  const int i = lane >> 3, j = lane & 7;

  const uint4* qp = (const uint4*)(Q + (size_t)t * E_ + i * D_);
  const uint4* kp = (const uint4*)(K + (size_t)t * E_ + j * D_);
  float acc = 0.f;
#pragma unroll
  for (int it = 0; it < 12; ++it) {   // 96 bf16 = 12 x uint4
    const uint4 qv = qp[it], kv = kp[it];
    acc += bflo(qv.x) * bflo(kv.x) + bfhi(qv.x) * bfhi(kv.x);
    acc += bflo(qv.y) * bflo(kv.y) + bfhi(qv.y) * bfhi(kv.y);
    acc += bflo(qv.z) * bflo(kv.z) + bfhi(qv.z) * bfhi(kv.z);
    acc += bflo(qv.w) * bflo(kv.w) + bfhi(qv.w) * bfhi(kv.w);
  }
  // mask==0 -> -1e20 everywhere -> softmax degenerates to 1/8
  float sv = (mask[t] == 0) ? -1e20f : acc;
  sv *= 0.03608439182435161f;          // 1/sqrt(768)
  float mx = sv;
  mx = fmaxf(mx, __shfl_xor(mx, 1));
  mx = fmaxf(mx, __shfl_xor(mx, 2));
  mx = fmaxf(mx, __shfl_xor(mx, 4));
  const float e = __expf(sv - mx);
  float sm = e;
  sm += __shfl_xor(sm, 1);
  sm += __shfl_xor(sm, 2);
  sm += __shfl_xor(sm, 4);
  pl[wave][i][j] = e / sm;
  __syncthreads();

  // PV: lane (i2, db) owns d = db*12 .. db*12+11 of head i2
  const int i2 = lane >> 3, db = lane & 7;
  float o[12] = {};
#pragma unroll
  for (int jj = 0; jj < 8; ++jj) {
    const float pj = pl[wave][i2][jj];
    const uint2* vp = (const uint2*)(V + (size_t)t * E_ + jj * D_ + db * 12);
    const uint2 v0 = vp[0], v1 = vp[1], v2 = vp[2];
    o[0]  += pj * bflo(v0.x);  o[1]  += pj * bfhi(v0.x);
    o[2]  += pj * bflo(v0.y);  o[3]  += pj * bfhi(v0.y);
    o[4]  += pj * bflo(v1.x);  o[5]  += pj * bfhi(v1.x);
    o[6]  += pj * bflo(v1.y);  o[7]  += pj * bfhi(v1.y);
    o[8]  += pj * bflo(v2.x);  o[9]  += pj * bfhi(v2.x);
    o[10] += pj * bflo(v2.y);  o[11] += pj * bfhi(v2.y);
  }
  // scrambled reshape [b,h,s,d] -> [b, 512h + s/8, 96(s%8)+d]
  const size_t row = (size_t)b * S_ + 512 * i2 + (s >> 3);
  u16* op = O + row * E_ + 96 * (s & 7) + db * 12;
  uint2 w0, w1, w2;
  w0.x = pk2(o[0], o[1]);
  w0.y = pk2(o[2], o[3]);
  w1.x = pk2(o[4], o[5]);
  w1.y = pk2(o[6], o[7]);
  w2.x = pk2(o[8], o[9]);
  w2.y = pk2(o[10], o[11]);
  ((uint2*)op)[0] = w0;
  ((uint2*)op)[1] = w1;
  ((uint2*)op)[2] = w2;
}

extern "C" void kernel_launch(void* const* d_in, const int* in_sizes, int n_in,
                              void* d_out, int out_size, void* d_ws, size_t ws_size,
                              hipStream_t stream)
{
  const float* values = (const float*)d_in[0];
  const float* keys   = (const float*)d_in[1];
  const float* query  = (const float*)d_in[2];
  const int*   mask   = (const int*)d_in[3];
  const float* Wv = (const float*)d_in[4];
  const float* Wk = (const float*)d_in[5];
  const float* Wq = (const float*)d_in[6];
  const float* Wo = (const float*)d_in[7];
  const float* bo = (const float*)d_in[8];

  const size_t TE = (size_t)T_ * E_;
  const size_t EE = (size_t)E_ * E_;
  u16* Qb = (u16*)d_ws;          // 25.2 MB each (bf16)
  u16* Kb = Qb + TE;
  u16* Vb = Kb + TE;
  u16* Xt = Vb + TE;             // A-convert scratch; later aliased as O2
  u16* Wb = Xt + TE;             // 4 x 1.18 MB bf16 weights (105.4 MB total)

  dim3 gg(T_ / 256 * (E_ / 256));   // 64 x 3 = 192 blocks
  dim3 gc(TE / 4 / 256);            // 12288 blocks

  conv_w<<<dim3(4 * (E_ * E_ / 4) / 256), dim3(256), 0, stream>>>(Wq, Wk, Wv, Wo, Wb);

  conv_bf16<<<gc, dim3(256), 0, stream>>>(query, Xt);
  gemm8<false, false><<<gg, dim3(512), 0, stream>>>(Xt, Wb + 0 * EE, nullptr, Qb);
  conv_bf16<<<gc, dim3(256), 0, stream>>>(keys, Xt);
  gemm8<false, false><<<gg, dim3(512), 0, stream>>>(Xt, Wb + 1 * EE, nullptr, Kb);
  conv_bf16<<<gc, dim3(256), 0, stream>>>(values, Xt);
  gemm8<false, false><<<gg, dim3(512), 0, stream>>>(Xt, Wb + 2 * EE, nullptr, Vb);

  attn_tok<<<dim3(T_ / 4), dim3(256), 0, stream>>>(Qb, Kb, Vb, mask, Xt /*O2*/);

  gemm8<true, true><<<gg, dim3(512), 0, stream>>>(Xt /*O2*/, Wb + 3 * EE, bo, (float*)d_out);
}